// Round 5
// baseline (516.592 us; speedup 1.0000x reference)
//
#include <hip/hip_runtime.h>
#include <stdint.h>

#define D_MODEL 1024
#define NHEAD   16
#define DK      64
#define BATCH   4
#define SEQ     2048
#define MTOT    (BATCH*SEQ)   // 8192
#define KVB     64
#define NT      (SEQ/KVB)     // 32

typedef __attribute__((ext_vector_type(4)))  float  f32x4;
typedef __attribute__((ext_vector_type(16))) float  f32x16;
typedef __attribute__((ext_vector_type(8)))  __bf16 bf16x8;
typedef __attribute__((ext_vector_type(8)))  unsigned short u16x8;
typedef __attribute__((ext_vector_type(4)))  unsigned int u32x4;

// Q scale: 1/sqrt(dk) * log2(e)  (softmax computed in exp2 domain)
#define QSCALE 0.1803368801111244f

__device__ __forceinline__ unsigned short f2bf(float f) {
    unsigned u = __builtin_bit_cast(unsigned, f);
    u += 0x7fffu + ((u >> 16) & 1u);
    return (unsigned short)(u >> 16);
}

// ---------------- convert x (fp32 -> bf16) ----------------
__global__ __launch_bounds__(256) void cvt_x_kernel(const float* __restrict__ x,
                                                    unsigned short* __restrict__ xb) {
    size_t i = ((size_t)blockIdx.x * 256 + threadIdx.x) * 8;
    f32x4 a = *(const f32x4*)(x + i);
    f32x4 b = *(const f32x4*)(x + i + 4);
    u16x8 o;
    o[0] = f2bf(a[0]); o[1] = f2bf(a[1]); o[2] = f2bf(a[2]); o[3] = f2bf(a[3]);
    o[4] = f2bf(b[0]); o[5] = f2bf(b[1]); o[6] = f2bf(b[2]); o[7] = f2bf(b[3]);
    *(u16x8*)(xb + i) = o;
}

// ------------- transpose+convert W[k][n] -> W^T[n][k] bf16 -------------
__global__ __launch_bounds__(256) void cvt_wt_kernel(const float* __restrict__ Wq,
                                                     const float* __restrict__ Wk,
                                                     const float* __restrict__ Wv,
                                                     unsigned short* __restrict__ wt) {
    __shared__ float tile[32][33];
    int mat = blockIdx.z;
    const float* W = (mat == 0) ? Wq : (mat == 1) ? Wk : Wv;
    int n0 = blockIdx.x * 32;
    int k0 = blockIdx.y * 32;
    int tx = threadIdx.x;       // 0..31
    int ty = threadIdx.y;       // 0..7
    #pragma unroll
    for (int i = 0; i < 4; ++i)
        tile[ty + i*8][tx] = W[(size_t)(k0 + ty + i*8) * D_MODEL + n0 + tx];
    __syncthreads();
    unsigned short* dst = wt + (size_t)mat * D_MODEL * D_MODEL;
    #pragma unroll
    for (int i = 0; i < 4; ++i)
        dst[(size_t)(n0 + ty + i*8) * D_MODEL + k0 + tx] = f2bf(tile[tx][ty + i*8]);
}

// ---------------- QKV projection GEMM ----------------
// Q,K stored as [b][h][s][dk]; V stored TRANSPOSED as [b][h][dk][s].
#define BM 128
#define BN 128
#define BKK 64
__global__ __launch_bounds__(256) void qkv_gemm_kernel(const unsigned short* __restrict__ xb,
                                                       const unsigned short* __restrict__ wt,
                                                       const float* __restrict__ bq,
                                                       const float* __restrict__ bk,
                                                       const float* __restrict__ bv,
                                                       unsigned short* __restrict__ qkv) {
    __shared__ __align__(16) unsigned char sA[BM * BKK * 2];
    __shared__ __align__(16) unsigned char sB[BN * BKK * 2];

    int nb   = blockIdx.x;            // 0..23
    int mb   = blockIdx.y;            // 0..63
    int mat  = nb >> 3;
    int col0 = (nb & 7) * BN;
    int m0   = mb * BM;
    int t    = threadIdx.x;
    int lane = t & 63;
    int w    = t >> 6;

    const unsigned short* wmat = wt + (size_t)mat * D_MODEL * D_MODEL;
    const float* bias = (mat == 0) ? bq : (mat == 1) ? bk : bv;

    f32x4 acc[4][4];
    #pragma unroll
    for (int i = 0; i < 4; ++i)
        #pragma unroll
        for (int j = 0; j < 4; ++j)
            acc[i][j] = (f32x4)0.0f;

    int rA = (w >> 1) * 64;
    int rB = (w & 1) * 64;

    for (int ks = 0; ks < D_MODEL / BKK; ++ks) {
        int K0 = ks * BKK;
        #pragma unroll
        for (int i = 0; i < 4; ++i) {
            int c   = t + 256 * i;
            int row = c >> 3;
            int kc  = c & 7;
            int swz = kc ^ (row & 7);
            const unsigned short* ga = xb + (size_t)(m0 + row) * D_MODEL + K0 + swz * 8;
            __builtin_amdgcn_global_load_lds(
                (const __attribute__((address_space(1))) void*)ga,
                (__attribute__((address_space(3))) void*)(sA + c * 16), 16, 0, 0);
            const unsigned short* gb = wmat + (size_t)(col0 + row) * D_MODEL + K0 + swz * 8;
            __builtin_amdgcn_global_load_lds(
                (const __attribute__((address_space(1))) void*)gb,
                (__attribute__((address_space(3))) void*)(sB + c * 16), 16, 0, 0);
        }
        __syncthreads();

        #pragma unroll
        for (int kk = 0; kk < 2; ++kk) {
            bf16x8 af[4], bf[4];
            int kc = kk * 4 + (lane >> 4);
            #pragma unroll
            for (int mt = 0; mt < 4; ++mt) {
                int row = rA + mt * 16 + (lane & 15);
                int swz = kc ^ (row & 7);
                af[mt] = *(const bf16x8*)(sA + row * 128 + swz * 16);
            }
            #pragma unroll
            for (int nt = 0; nt < 4; ++nt) {
                int row = rB + nt * 16 + (lane & 15);
                int swz = kc ^ (row & 7);
                bf[nt] = *(const bf16x8*)(sB + row * 128 + swz * 16);
            }
            #pragma unroll
            for (int mt = 0; mt < 4; ++mt)
                #pragma unroll
                for (int nt = 0; nt < 4; ++nt)
                    acc[mt][nt] = __builtin_amdgcn_mfma_f32_16x16x32_bf16(
                        af[mt], bf[nt], acc[mt][nt], 0, 0, 0);
        }
        __syncthreads();
    }

    #pragma unroll
    for (int mt = 0; mt < 4; ++mt) {
        #pragma unroll
        for (int nt = 0; nt < 4; ++nt) {
            int gn = col0 + rB + nt * 16 + (lane & 15);
            float bval = bias[gn];
            #pragma unroll
            for (int r = 0; r < 4; ++r) {
                int gm = m0 + rA + mt * 16 + (lane >> 4) * 4 + r;
                float v = acc[mt][nt][r] + bval;
                if (mat == 0) v *= QSCALE;   // fold 1/sqrt(dk)*log2e into Q
                int b = gm >> 11, s = gm & 2047;
                int h = gn >> 6,  d = gn & 63;
                size_t idx;
                if (mat == 2)   // V transposed: [b][h][d][s]
                    idx = ((size_t)(b * NHEAD + h) * DK + d) * SEQ + s;
                else            // Q,K: [b][h][s][d]
                    idx = ((size_t)(b * NHEAD + h) * SEQ + s) * DK + d;
                qkv[(size_t)mat * MTOT * D_MODEL + idx] = f2bf(v);
            }
        }
    }
}

// ---------------- fused flash attention (swapped-QK^T, 32x32 MFMA, no LDS) ----------------
// grid: (64 bh, 16 q-blocks of 128), 256 threads = 4 waves, each wave 32 q-rows.
// Register-pipelined 2-deep: K(t+1) issued after QK^T(t); V(t+1) after PV(t).
#define CVTPK(dst, lo_, hi_) \
    asm("v_cvt_pk_bf16_f32 %0, %1, %2" : "=v"(dst) : "v"(lo_), "v"(hi_))
#define PLSWAP(x_, y_) \
    asm("v_permlane32_swap_b32 %0, %1" : "+v"(x_), "+v"(y_))
#define EXP2(dst, x_) \
    asm("v_exp_f32 %0, %1" : "=v"(dst) : "v"(x_))

// P^T B-frag from 8 per-lane P values (C-layout kv rows) via cvt_pk+permlane32_swap.
__device__ __forceinline__ bf16x8 make_pf(float p0, float p1, float p2, float p3,
                                          float p4, float p5, float p6, float p7) {
    unsigned a1, a2, b1, b2;
    CVTPK(a1, p0, p1); CVTPK(a2, p2, p3);
    CVTPK(b1, p4, p5); CVTPK(b2, p6, p7);
    PLSWAP(a1, b1); PLSWAP(a2, b2);
    u32x4 u = { a1, a2, b1, b2 };
    return __builtin_bit_cast(bf16x8, u);
}

__device__ __forceinline__ float vmax16(const f32x16& v) {
    float a = fmaxf(fmaxf(v[0], v[1]),   fmaxf(v[2], v[3]));
    float b = fmaxf(fmaxf(v[4], v[5]),   fmaxf(v[6], v[7]));
    float c = fmaxf(fmaxf(v[8], v[9]),   fmaxf(v[10], v[11]));
    float d = fmaxf(fmaxf(v[12], v[13]), fmaxf(v[14], v[15]));
    return fmaxf(fmaxf(a, b), fmaxf(c, d));
}

__global__ __launch_bounds__(256, 3) void attn_kernel(const unsigned short* __restrict__ qkv,
                                                      float* __restrict__ out) {
    int bh = blockIdx.x;      // b*16 + h
    int qb = blockIdx.y;      // 0..15
    int lane = threadIdx.x & 63;
    int w = threadIdx.x >> 6;
    int hi = lane >> 5;       // 0/1
    int l31 = lane & 31;

    const unsigned short* Qb = qkv + (size_t)bh * SEQ * DK;
    const unsigned short* Kb = qkv + (size_t)MTOT * D_MODEL + (size_t)bh * SEQ * DK;
    const unsigned short* Vt = qkv + (size_t)2 * MTOT * D_MODEL + (size_t)bh * DK * SEQ; // [d][s]

    int qbase = qb * 128 + w * 32;

    // Q B-frags: col=q=lane&31, k=d=kd*16+hi*8+j   (Q pre-scaled by 1/8*log2e)
    bf16x8 aq[4];
    #pragma unroll
    for (int kd = 0; kd < 4; ++kd)
        aq[kd] = *(const bf16x8*)(Qb + (size_t)(qbase + l31) * DK + kd * 16 + hi * 8);

    f32x16 o0 = (f32x16)0.0f, o1 = (f32x16)0.0f;   // O^T[d][q], d-halves 0/1
    float mrun = -3e38f, lrun = 0.0f;

    const unsigned short* kbase = Kb + (size_t)l31 * DK + hi * 8;
    const unsigned short* vbase = Vt + (size_t)l31 * SEQ + hi * 8;

#define LOADK(K0_, K1_, tile_) do {                                              \
    const unsigned short* kp_ = kbase + (size_t)(tile_) * KVB * DK;              \
    K0_[0] = *(const bf16x8*)(kp_);       K0_[1] = *(const bf16x8*)(kp_ + 16);   \
    K0_[2] = *(const bf16x8*)(kp_ + 32);  K0_[3] = *(const bf16x8*)(kp_ + 48);   \
    const unsigned short* kq_ = kp_ + 32 * DK;                                   \
    K1_[0] = *(const bf16x8*)(kq_);       K1_[1] = *(const bf16x8*)(kq_ + 16);   \
    K1_[2] = *(const bf16x8*)(kq_ + 32);  K1_[3] = *(const bf16x8*)(kq_ + 48);   \
} while (0)

#define LOADV(V0_, V1_, tile_) do {                                              \
    const unsigned short* vp_ = vbase + (size_t)(tile_) * KVB;                   \
    V0_[0] = *(const bf16x8*)(vp_);       V0_[1] = *(const bf16x8*)(vp_ + 16);   \
    V0_[2] = *(const bf16x8*)(vp_ + 32);  V0_[3] = *(const bf16x8*)(vp_ + 48);   \
    const unsigned short* vq_ = vp_ + 32 * SEQ;                                  \
    V1_[0] = *(const bf16x8*)(vq_);       V1_[1] = *(const bf16x8*)(vq_ + 16);   \
    V1_[2] = *(const bf16x8*)(vq_ + 32);  V1_[3] = *(const bf16x8*)(vq_ + 48);   \
} while (0)

#define STEP(K0_, K1_, V0_, V1_, NK0_, NK1_, NV0_, NV1_, kt_) do {               \
    int nxt_ = ((kt_) + 1 < NT) ? (kt_) + 1 : NT - 1;                            \
    /* S^T = K Q^T */                                                            \
    f32x16 sc0 = (f32x16)0.0f, sc1 = (f32x16)0.0f;                               \
    __builtin_amdgcn_s_setprio(1);                                               \
    _Pragma("unroll")                                                            \
    for (int kd = 0; kd < 4; ++kd) {                                             \
        sc0 = __builtin_amdgcn_mfma_f32_32x32x16_bf16(K0_[kd], aq[kd], sc0, 0, 0, 0); \
        sc1 = __builtin_amdgcn_mfma_f32_32x32x16_bf16(K1_[kd], aq[kd], sc1, 0, 0, 0); \
    }                                                                            \
    __builtin_amdgcn_s_setprio(0);                                               \
    LOADK(NK0_, NK1_, nxt_);   /* prefetch next K under softmax+PV */            \
    /* online softmax in exp2 domain, defer-max THR=8 */                         \
    float mx = fmaxf(vmax16(sc0), vmax16(sc1));                                  \
    mx = fmaxf(mx, __shfl_xor(mx, 32));                                          \
    if (!__all(mx <= mrun + 8.0f)) {                                             \
        float mnew = fmaxf(mrun, mx);                                            \
        float al;  EXP2(al, mrun - mnew);                                        \
        lrun *= al;                                                              \
        _Pragma("unroll")                                                        \
        for (int i = 0; i < 16; ++i) { o0[i] *= al; o1[i] *= al; }               \
        mrun = mnew;                                                             \
    }                                                                            \
    float r0_ = 0.f, r1_ = 0.f, r2_ = 0.f, r3_ = 0.f;                            \
    _Pragma("unroll")                                                            \
    for (int i = 0; i < 16; ++i) { float p; EXP2(p, sc0[i] - mrun); sc0[i] = p; } \
    _Pragma("unroll")                                                            \
    for (int i = 0; i < 16; ++i) { float p; EXP2(p, sc1[i] - mrun); sc1[i] = p; } \
    _Pragma("unroll")                                                            \
    for (int i = 0; i < 4; ++i) {                                                \
        r0_ += sc0[i] + sc1[i];     r1_ += sc0[4+i] + sc1[4+i];                  \
        r2_ += sc0[8+i] + sc1[8+i]; r3_ += sc0[12+i] + sc1[12+i];                \
    }                                                                            \
    float rs = (r0_ + r1_) + (r2_ + r3_);                                        \
    rs += __shfl_xor(rs, 32);                                                    \
    lrun += rs;                                                                  \
    /* P^T -> bf16 B-frags */                                                    \
    bf16x8 pf0 = make_pf(sc0[0], sc0[1], sc0[2],  sc0[3],  sc0[4],  sc0[5],  sc0[6],  sc0[7]);  \
    bf16x8 pf1 = make_pf(sc0[8], sc0[9], sc0[10], sc0[11], sc0[12], sc0[13], sc0[14], sc0[15]); \
    bf16x8 pf2 = make_pf(sc1[0], sc1[1], sc1[2],  sc1[3],  sc1[4],  sc1[5],  sc1[6],  sc1[7]);  \
    bf16x8 pf3 = make_pf(sc1[8], sc1[9], sc1[10], sc1[11], sc1[12], sc1[13], sc1[14], sc1[15]); \
    /* O^T += V^T P^T */                                                         \
    __builtin_amdgcn_s_setprio(1);                                               \
    o0 = __builtin_amdgcn_mfma_f32_32x32x16_bf16(V0_[0], pf0, o0, 0, 0, 0);      \
    o1 = __builtin_amdgcn_mfma_f32_32x32x16_bf16(V1_[0], pf0, o1, 0, 0, 0);      \
    o0 = __builtin_amdgcn_mfma_f32_32x32x16_bf16(V0_[1], pf1, o0, 0, 0, 0);      \
    o1 = __builtin_amdgcn_mfma_f32_32x32x16_bf16(V1_[1], pf1, o1, 0, 0, 0);      \
    o0 = __builtin_amdgcn_mfma_f32_32x32x16_bf16(V0_[2], pf2, o0, 0, 0, 0);      \
    o1 = __builtin_amdgcn_mfma_f32_32x32x16_bf16(V1_[2], pf2, o1, 0, 0, 0);      \
    o0 = __builtin_amdgcn_mfma_f32_32x32x16_bf16(V0_[3], pf3, o0, 0, 0, 0);      \
    o1 = __builtin_amdgcn_mfma_f32_32x32x16_bf16(V1_[3], pf3, o1, 0, 0, 0);      \
    __builtin_amdgcn_s_setprio(0);                                               \
    LOADV(NV0_, NV1_, nxt_);   /* prefetch next V under next QK^T+softmax */     \
} while (0)

    bf16x8 ka0[4], ka1[4], va0[4], va1[4];
    bf16x8 kb0[4], kb1[4], vb0[4], vb1[4];
    LOADK(ka0, ka1, 0);
    LOADV(va0, va1, 0);

    for (int kt = 0; kt < NT; kt += 2) {
        STEP(ka0, ka1, va0, va1, kb0, kb1, vb0, vb1, kt);
        STEP(kb0, kb1, vb0, vb1, ka0, ka1, va0, va1, kt + 1);
    }

#undef STEP
#undef LOADK
#undef LOADV

    // ---- epilogue: direct f32x4 stores (C rows are 4-contiguous in d) ----
    int b = bh >> 4, h = bh & 15;
    float rl = 1.0f / lrun;
    float* dst = out + ((size_t)b * SEQ + qbase + l31) * D_MODEL + h * DK;
    #pragma unroll
    for (int g = 0; g < 4; ++g) {
        int d0 = 8 * g + 4 * hi;
        f32x4 v0 = { o0[4*g] * rl, o0[4*g+1] * rl, o0[4*g+2] * rl, o0[4*g+3] * rl };
        *(f32x4*)(dst + d0) = v0;
        f32x4 v1 = { o1[4*g] * rl, o1[4*g+1] * rl, o1[4*g+2] * rl, o1[4*g+3] * rl };
        *(f32x4*)(dst + 32 + d0) = v1;
    }
}

extern "C" void kernel_launch(void* const* d_in, const int* in_sizes, int n_in,
                              void* d_out, int out_size, void* d_ws, size_t ws_size,
                              hipStream_t stream) {
    const float* x  = (const float*)d_in[0];
    const float* Wq = (const float*)d_in[1];
    const float* bq = (const float*)d_in[2];
    const float* Wk = (const float*)d_in[3];
    const float* bk = (const float*)d_in[4];
    const float* Wv = (const float*)d_in[5];
    const float* bv = (const float*)d_in[6];
    float* out = (float*)d_out;

    unsigned short* xb  = (unsigned short*)d_ws;                       // 16 MB
    unsigned short* wt  = xb + (size_t)MTOT * D_MODEL;                 // 6 MB
    unsigned short* qkv = wt + (size_t)3 * D_MODEL * D_MODEL;          // 48 MB

    cvt_x_kernel<<<dim3(MTOT * D_MODEL / (256 * 8)), dim3(256), 0, stream>>>(x, xb);
    cvt_wt_kernel<<<dim3(32, 32, 3), dim3(32, 8), 0, stream>>>(Wq, Wk, Wv, wt);
    qkv_gemm_kernel<<<dim3(24, 64), dim3(256), 0, stream>>>(xb, wt, bq, bk, bv, qkv);
    attn_kernel<<<dim3(64, 16), dim3(256), 0, stream>>>(qkv, out);
}

// Round 6
// 202.333 us; speedup vs baseline: 2.5532x; 2.5532x over previous
//
#include <hip/hip_runtime.h>
#include <stdint.h>

#define D_MODEL 1024
#define NHEAD   16
#define DK      64
#define BATCH   4
#define SEQ     2048
#define MTOT    (BATCH*SEQ)   // 8192
#define KVB     64
#define NT      (SEQ/KVB)     // 32

typedef __attribute__((ext_vector_type(4)))  float  f32x4;
typedef __attribute__((ext_vector_type(16))) float  f32x16;
typedef __attribute__((ext_vector_type(8)))  __bf16 bf16x8;
typedef __attribute__((ext_vector_type(8)))  unsigned short u16x8;
typedef __attribute__((ext_vector_type(4)))  unsigned int u32x4;

// Q scale: 1/sqrt(dk) * log2(e)  (softmax computed in exp2 domain)
#define QSCALE 0.1803368801111244f

__device__ __forceinline__ unsigned short f2bf(float f) {
    unsigned u = __builtin_bit_cast(unsigned, f);
    u += 0x7fffu + ((u >> 16) & 1u);
    return (unsigned short)(u >> 16);
}

// ---------------- convert x (fp32 -> bf16) ----------------
__global__ __launch_bounds__(256) void cvt_x_kernel(const float* __restrict__ x,
                                                    unsigned short* __restrict__ xb) {
    size_t i = ((size_t)blockIdx.x * 256 + threadIdx.x) * 8;
    f32x4 a = *(const f32x4*)(x + i);
    f32x4 b = *(const f32x4*)(x + i + 4);
    u16x8 o;
    o[0] = f2bf(a[0]); o[1] = f2bf(a[1]); o[2] = f2bf(a[2]); o[3] = f2bf(a[3]);
    o[4] = f2bf(b[0]); o[5] = f2bf(b[1]); o[6] = f2bf(b[2]); o[7] = f2bf(b[3]);
    *(u16x8*)(xb + i) = o;
}

// ------------- transpose+convert W[k][n] -> W^T[n][k] bf16 -------------
__global__ __launch_bounds__(256) void cvt_wt_kernel(const float* __restrict__ Wq,
                                                     const float* __restrict__ Wk,
                                                     const float* __restrict__ Wv,
                                                     unsigned short* __restrict__ wt) {
    __shared__ float tile[32][33];
    int mat = blockIdx.z;
    const float* W = (mat == 0) ? Wq : (mat == 1) ? Wk : Wv;
    int n0 = blockIdx.x * 32;
    int k0 = blockIdx.y * 32;
    int tx = threadIdx.x;       // 0..31
    int ty = threadIdx.y;       // 0..7
    #pragma unroll
    for (int i = 0; i < 4; ++i)
        tile[ty + i*8][tx] = W[(size_t)(k0 + ty + i*8) * D_MODEL + n0 + tx];
    __syncthreads();
    unsigned short* dst = wt + (size_t)mat * D_MODEL * D_MODEL;
    #pragma unroll
    for (int i = 0; i < 4; ++i)
        dst[(size_t)(n0 + ty + i*8) * D_MODEL + k0 + tx] = f2bf(tile[tx][ty + i*8]);
}

// ---------------- QKV projection GEMM ----------------
// Q,K stored as [b][h][s][dk]; V stored TRANSPOSED as [b][h][dk][s].
#define BM 128
#define BN 128
#define BKK 64
__global__ __launch_bounds__(256) void qkv_gemm_kernel(const unsigned short* __restrict__ xb,
                                                       const unsigned short* __restrict__ wt,
                                                       const float* __restrict__ bq,
                                                       const float* __restrict__ bk,
                                                       const float* __restrict__ bv,
                                                       unsigned short* __restrict__ qkv) {
    __shared__ __align__(16) unsigned char sA[BM * BKK * 2];
    __shared__ __align__(16) unsigned char sB[BN * BKK * 2];

    int nb   = blockIdx.x;            // 0..23
    int mb   = blockIdx.y;            // 0..63
    int mat  = nb >> 3;
    int col0 = (nb & 7) * BN;
    int m0   = mb * BM;
    int t    = threadIdx.x;
    int lane = t & 63;
    int w    = t >> 6;

    const unsigned short* wmat = wt + (size_t)mat * D_MODEL * D_MODEL;
    const float* bias = (mat == 0) ? bq : (mat == 1) ? bk : bv;

    f32x4 acc[4][4];
    #pragma unroll
    for (int i = 0; i < 4; ++i)
        #pragma unroll
        for (int j = 0; j < 4; ++j)
            acc[i][j] = (f32x4)0.0f;

    int rA = (w >> 1) * 64;
    int rB = (w & 1) * 64;

    for (int ks = 0; ks < D_MODEL / BKK; ++ks) {
        int K0 = ks * BKK;
        #pragma unroll
        for (int i = 0; i < 4; ++i) {
            int c   = t + 256 * i;
            int row = c >> 3;
            int kc  = c & 7;
            int swz = kc ^ (row & 7);
            const unsigned short* ga = xb + (size_t)(m0 + row) * D_MODEL + K0 + swz * 8;
            __builtin_amdgcn_global_load_lds(
                (const __attribute__((address_space(1))) void*)ga,
                (__attribute__((address_space(3))) void*)(sA + c * 16), 16, 0, 0);
            const unsigned short* gb = wmat + (size_t)(col0 + row) * D_MODEL + K0 + swz * 8;
            __builtin_amdgcn_global_load_lds(
                (const __attribute__((address_space(1))) void*)gb,
                (__attribute__((address_space(3))) void*)(sB + c * 16), 16, 0, 0);
        }
        __syncthreads();

        #pragma unroll
        for (int kk = 0; kk < 2; ++kk) {
            bf16x8 af[4], bf[4];
            int kc = kk * 4 + (lane >> 4);
            #pragma unroll
            for (int mt = 0; mt < 4; ++mt) {
                int row = rA + mt * 16 + (lane & 15);
                int swz = kc ^ (row & 7);
                af[mt] = *(const bf16x8*)(sA + row * 128 + swz * 16);
            }
            #pragma unroll
            for (int nt = 0; nt < 4; ++nt) {
                int row = rB + nt * 16 + (lane & 15);
                int swz = kc ^ (row & 7);
                bf[nt] = *(const bf16x8*)(sB + row * 128 + swz * 16);
            }
            #pragma unroll
            for (int mt = 0; mt < 4; ++mt)
                #pragma unroll
                for (int nt = 0; nt < 4; ++nt)
                    acc[mt][nt] = __builtin_amdgcn_mfma_f32_16x16x32_bf16(
                        af[mt], bf[nt], acc[mt][nt], 0, 0, 0);
        }
        __syncthreads();
    }

    #pragma unroll
    for (int mt = 0; mt < 4; ++mt) {
        #pragma unroll
        for (int nt = 0; nt < 4; ++nt) {
            int gn = col0 + rB + nt * 16 + (lane & 15);
            float bval = bias[gn];
            #pragma unroll
            for (int r = 0; r < 4; ++r) {
                int gm = m0 + rA + mt * 16 + (lane >> 4) * 4 + r;
                float v = acc[mt][nt][r] + bval;
                if (mat == 0) v *= QSCALE;   // fold 1/sqrt(dk)*log2e into Q
                int b = gm >> 11, s = gm & 2047;
                int h = gn >> 6,  d = gn & 63;
                size_t idx;
                if (mat == 2)   // V transposed: [b][h][d][s]
                    idx = ((size_t)(b * NHEAD + h) * DK + d) * SEQ + s;
                else            // Q,K: [b][h][s][d]
                    idx = ((size_t)(b * NHEAD + h) * SEQ + s) * DK + d;
                qkv[(size_t)mat * MTOT * D_MODEL + idx] = f2bf(v);
            }
        }
    }
}

// ---------------- fused flash attention (swapped-QK^T, 32x32 MFMA, LDS-staged) ----------------
// grid: (64 bh, 16 q-blocks of 128), 256 threads = 4 waves, each wave 32 q-rows.
// K and V^T double-buffered in LDS via global_load_lds (XOR-swizzled, rule #21:
// pre-swizzled source + swizzled read). One barrier per KV tile (2-phase T3 recipe).
// LDS map: [0,8192) K buf0 | [8192,16384) K buf1 | [16384,24576) V^T buf0 | [24576,32768) V^T buf1
#define CVTPK(dst, lo_, hi_) \
    asm("v_cvt_pk_bf16_f32 %0, %1, %2" : "=v"(dst) : "v"(lo_), "v"(hi_))
#define PLSWAP(x_, y_) \
    asm("v_permlane32_swap_b32 %0, %1" : "+v"(x_), "+v"(y_))
#define EXP2(dst, x_) \
    asm("v_exp_f32 %0, %1" : "=v"(dst) : "v"(x_))

// P^T B-frag from 8 per-lane P values (C-layout kv rows) via cvt_pk+permlane32_swap.
__device__ __forceinline__ bf16x8 make_pf(float p0, float p1, float p2, float p3,
                                          float p4, float p5, float p6, float p7) {
    unsigned a1, a2, b1, b2;
    CVTPK(a1, p0, p1); CVTPK(a2, p2, p3);
    CVTPK(b1, p4, p5); CVTPK(b2, p6, p7);
    PLSWAP(a1, b1); PLSWAP(a2, b2);
    u32x4 u = { a1, a2, b1, b2 };
    return __builtin_bit_cast(bf16x8, u);
}

__device__ __forceinline__ float vmax16(const f32x16& v) {
    float a = fmaxf(fmaxf(v[0], v[1]),   fmaxf(v[2], v[3]));
    float b = fmaxf(fmaxf(v[4], v[5]),   fmaxf(v[6], v[7]));
    float c = fmaxf(fmaxf(v[8], v[9]),   fmaxf(v[10], v[11]));
    float d = fmaxf(fmaxf(v[12], v[13]), fmaxf(v[14], v[15]));
    return fmaxf(fmaxf(a, b), fmaxf(c, d));
}

__global__ __launch_bounds__(256, 3) void attn_kernel(const unsigned short* __restrict__ qkv,
                                                      float* __restrict__ out) {
    __shared__ __align__(16) unsigned char lds[32768];

    int bh = blockIdx.x;      // b*16 + h
    int qb = blockIdx.y;      // 0..15
    int t = threadIdx.x;
    int lane = t & 63;
    int w = t >> 6;
    int hi = lane >> 5;       // 0/1
    int l31 = lane & 31;

    const unsigned short* Qb = qkv + (size_t)bh * SEQ * DK;
    const unsigned short* Kb = qkv + (size_t)MTOT * D_MODEL + (size_t)bh * SEQ * DK;
    const unsigned short* Vt = qkv + (size_t)2 * MTOT * D_MODEL + (size_t)bh * DK * SEQ; // [d][s]

    int qbase = qb * 128 + w * 32;

    // Q B-frags: col=q=lane&31, k=d=kd*16+hi*8+j   (Q pre-scaled by 1/8*log2e)
    bf16x8 aq[4];
    #pragma unroll
    for (int kd = 0; kd < 4; ++kd)
        aq[kd] = *(const bf16x8*)(Qb + (size_t)(qbase + l31) * DK + kd * 16 + hi * 8);

    f32x16 o0 = (f32x16)0.0f, o1 = (f32x16)0.0f;   // O^T[d][q], d-halves 0/1
    float mrun = -3e38f, lrun = 0.0f;

    // Stage tile: K[64 rows][8 chunks], V^T[64 d-rows][8 kv-chunks]; source
    // chunk pre-swizzled (kc ^ (row&7)) so swizzled ds_read lands on the right data.
#define STAGE(tile_, bo_) do {                                                         \
    int kv0_ = (tile_) * KVB;                                                          \
    _Pragma("unroll")                                                                  \
    for (int i_ = 0; i_ < 2; ++i_) {                                                   \
        int c_ = t + 256 * i_;                                                         \
        int row_ = c_ >> 3, kc_ = c_ & 7;                                              \
        int sw_ = (kc_ ^ (row_ & 7)) * 8;                                              \
        __builtin_amdgcn_global_load_lds(                                              \
            (const __attribute__((address_space(1))) void*)(Kb + (size_t)(kv0_ + row_) * DK + sw_), \
            (__attribute__((address_space(3))) void*)(lds + (bo_) + c_ * 16), 16, 0, 0);            \
        __builtin_amdgcn_global_load_lds(                                              \
            (const __attribute__((address_space(1))) void*)(Vt + (size_t)row_ * SEQ + kv0_ + sw_),  \
            (__attribute__((address_space(3))) void*)(lds + 16384 + (bo_) + c_ * 16), 16, 0, 0);    \
    }                                                                                  \
} while (0)

    int swz7 = l31 & 7;
    // chunk byte offsets for the 4 k-chunks this lane reads (same for K and V^T)
    int cofs0 = ((0 + hi) ^ swz7) << 4;
    int cofs1 = ((2 + hi) ^ swz7) << 4;
    int cofs2 = ((4 + hi) ^ swz7) << 4;
    int cofs3 = ((6 + hi) ^ swz7) << 4;

    STAGE(0, 0);
    __syncthreads();
    int buf = 0;

    for (int kt = 0; kt < NT; ++kt) {
        if (kt + 1 < NT)
            STAGE(kt + 1, (buf ^ 1) * 8192);

        const unsigned char* kb = lds + buf * 8192;
        const unsigned char* vb = lds + 16384 + buf * 8192;
        const unsigned char* kr0 = kb + l31 * 128;
        const unsigned char* kr1 = kb + (32 + l31) * 128;
        const unsigned char* vr0 = vb + l31 * 128;
        const unsigned char* vr1 = vb + (32 + l31) * 128;

        // ---- S^T = K Q^T ----
        bf16x8 ak00 = *(const bf16x8*)(kr0 + cofs0);
        bf16x8 ak01 = *(const bf16x8*)(kr0 + cofs1);
        bf16x8 ak02 = *(const bf16x8*)(kr0 + cofs2);
        bf16x8 ak03 = *(const bf16x8*)(kr0 + cofs3);
        bf16x8 ak10 = *(const bf16x8*)(kr1 + cofs0);
        bf16x8 ak11 = *(const bf16x8*)(kr1 + cofs1);
        bf16x8 ak12 = *(const bf16x8*)(kr1 + cofs2);
        bf16x8 ak13 = *(const bf16x8*)(kr1 + cofs3);
        f32x16 sc0 = (f32x16)0.0f, sc1 = (f32x16)0.0f;
        __builtin_amdgcn_s_setprio(1);
        sc0 = __builtin_amdgcn_mfma_f32_32x32x16_bf16(ak00, aq[0], sc0, 0, 0, 0);
        sc1 = __builtin_amdgcn_mfma_f32_32x32x16_bf16(ak10, aq[0], sc1, 0, 0, 0);
        sc0 = __builtin_amdgcn_mfma_f32_32x32x16_bf16(ak01, aq[1], sc0, 0, 0, 0);
        sc1 = __builtin_amdgcn_mfma_f32_32x32x16_bf16(ak11, aq[1], sc1, 0, 0, 0);
        sc0 = __builtin_amdgcn_mfma_f32_32x32x16_bf16(ak02, aq[2], sc0, 0, 0, 0);
        sc1 = __builtin_amdgcn_mfma_f32_32x32x16_bf16(ak12, aq[2], sc1, 0, 0, 0);
        sc0 = __builtin_amdgcn_mfma_f32_32x32x16_bf16(ak03, aq[3], sc0, 0, 0, 0);
        sc1 = __builtin_amdgcn_mfma_f32_32x32x16_bf16(ak13, aq[3], sc1, 0, 0, 0);
        __builtin_amdgcn_s_setprio(0);

        // ---- V^T frags issued now; latency hides under softmax VALU ----
        bf16x8 av00 = *(const bf16x8*)(vr0 + cofs0);
        bf16x8 av01 = *(const bf16x8*)(vr0 + cofs1);
        bf16x8 av02 = *(const bf16x8*)(vr0 + cofs2);
        bf16x8 av03 = *(const bf16x8*)(vr0 + cofs3);
        bf16x8 av10 = *(const bf16x8*)(vr1 + cofs0);
        bf16x8 av11 = *(const bf16x8*)(vr1 + cofs1);
        bf16x8 av12 = *(const bf16x8*)(vr1 + cofs2);
        bf16x8 av13 = *(const bf16x8*)(vr1 + cofs3);

        // ---- online softmax (exp2 domain), defer-max THR=8 ----
        float mx = fmaxf(vmax16(sc0), vmax16(sc1));
        mx = fmaxf(mx, __shfl_xor(mx, 32));
        if (!__all(mx <= mrun + 8.0f)) {
            float mnew = fmaxf(mrun, mx);
            float al;  EXP2(al, mrun - mnew);
            lrun *= al;
            #pragma unroll
            for (int i = 0; i < 16; ++i) { o0[i] *= al; o1[i] *= al; }
            mrun = mnew;
        }
        #pragma unroll
        for (int i = 0; i < 16; ++i) { float p; EXP2(p, sc0[i] - mrun); sc0[i] = p; }
        #pragma unroll
        for (int i = 0; i < 16; ++i) { float p; EXP2(p, sc1[i] - mrun); sc1[i] = p; }
        float r0 = 0.f, r1 = 0.f, r2 = 0.f, r3 = 0.f;
        #pragma unroll
        for (int i = 0; i < 4; ++i) {
            r0 += sc0[i] + sc1[i];     r1 += sc0[4+i] + sc1[4+i];
            r2 += sc0[8+i] + sc1[8+i]; r3 += sc0[12+i] + sc1[12+i];
        }
        float rs = (r0 + r1) + (r2 + r3);
        rs += __shfl_xor(rs, 32);
        lrun += rs;

        // ---- P^T -> bf16 B-frags ----
        bf16x8 pf0 = make_pf(sc0[0], sc0[1], sc0[2],  sc0[3],  sc0[4],  sc0[5],  sc0[6],  sc0[7]);
        bf16x8 pf1 = make_pf(sc0[8], sc0[9], sc0[10], sc0[11], sc0[12], sc0[13], sc0[14], sc0[15]);
        bf16x8 pf2 = make_pf(sc1[0], sc1[1], sc1[2],  sc1[3],  sc1[4],  sc1[5],  sc1[6],  sc1[7]);
        bf16x8 pf3 = make_pf(sc1[8], sc1[9], sc1[10], sc1[11], sc1[12], sc1[13], sc1[14], sc1[15]);

        // ---- O^T += V^T P^T ----
        __builtin_amdgcn_s_setprio(1);
        o0 = __builtin_amdgcn_mfma_f32_32x32x16_bf16(av00, pf0, o0, 0, 0, 0);
        o1 = __builtin_amdgcn_mfma_f32_32x32x16_bf16(av10, pf0, o1, 0, 0, 0);
        o0 = __builtin_amdgcn_mfma_f32_32x32x16_bf16(av01, pf1, o0, 0, 0, 0);
        o1 = __builtin_amdgcn_mfma_f32_32x32x16_bf16(av11, pf1, o1, 0, 0, 0);
        o0 = __builtin_amdgcn_mfma_f32_32x32x16_bf16(av02, pf2, o0, 0, 0, 0);
        o1 = __builtin_amdgcn_mfma_f32_32x32x16_bf16(av12, pf2, o1, 0, 0, 0);
        o0 = __builtin_amdgcn_mfma_f32_32x32x16_bf16(av03, pf3, o0, 0, 0, 0);
        o1 = __builtin_amdgcn_mfma_f32_32x32x16_bf16(av13, pf3, o1, 0, 0, 0);
        __builtin_amdgcn_s_setprio(0);

        __syncthreads();    // drains this wave's staging (vmcnt) + protects buffers
        buf ^= 1;
    }
#undef STAGE

    // ---- epilogue: direct f32x4 stores (C rows are 4-contiguous in d) ----
    int b = bh >> 4, h = bh & 15;
    float rl = 1.0f / lrun;
    float* dst = out + ((size_t)b * SEQ + qbase + l31) * D_MODEL + h * DK;
    #pragma unroll
    for (int g = 0; g < 4; ++g) {
        int d0 = 8 * g + 4 * hi;
        f32x4 v0 = { o0[4*g] * rl, o0[4*g+1] * rl, o0[4*g+2] * rl, o0[4*g+3] * rl };
        *(f32x4*)(dst + d0) = v0;
        f32x4 v1 = { o1[4*g] * rl, o1[4*g+1] * rl, o1[4*g+2] * rl, o1[4*g+3] * rl };
        *(f32x4*)(dst + 32 + d0) = v1;
    }
}

extern "C" void kernel_launch(void* const* d_in, const int* in_sizes, int n_in,
                              void* d_out, int out_size, void* d_ws, size_t ws_size,
                              hipStream_t stream) {
    const float* x  = (const float*)d_in[0];
    const float* Wq = (const float*)d_in[1];
    const float* bq = (const float*)d_in[2];
    const float* Wk = (const float*)d_in[3];
    const float* bk = (const float*)d_in[4];
    const float* Wv = (const float*)d_in[5];
    const float* bv = (const float*)d_in[6];
    float* out = (float*)d_out;

    unsigned short* xb  = (unsigned short*)d_ws;                       // 16 MB
    unsigned short* wt  = xb + (size_t)MTOT * D_MODEL;                 // 6 MB
    unsigned short* qkv = wt + (size_t)3 * D_MODEL * D_MODEL;          // 48 MB

    cvt_x_kernel<<<dim3(MTOT * D_MODEL / (256 * 8)), dim3(256), 0, stream>>>(x, xb);
    cvt_wt_kernel<<<dim3(32, 32, 3), dim3(32, 8), 0, stream>>>(Wq, Wk, Wv, wt);
    qkv_gemm_kernel<<<dim3(24, 64), dim3(256), 0, stream>>>(xb, wt, bq, bk, bv, qkv);
    attn_kernel<<<dim3(64, 16), dim3(256), 0, stream>>>(qkv, out);
}

// Round 9
// 200.983 us; speedup vs baseline: 2.5703x; 1.0067x over previous
//
#include <hip/hip_runtime.h>
#include <stdint.h>

#define D_MODEL 1024
#define NHEAD   16
#define DK      64
#define BATCH   4
#define SEQ     2048
#define MTOT    (BATCH*SEQ)   // 8192
#define KVB     64
#define NT      (SEQ/KVB)     // 32

typedef __attribute__((ext_vector_type(4)))  float  f32x4;
typedef __attribute__((ext_vector_type(16))) float  f32x16;
typedef __attribute__((ext_vector_type(8)))  __bf16 bf16x8;
typedef __attribute__((ext_vector_type(8)))  unsigned short u16x8;
typedef __attribute__((ext_vector_type(4)))  unsigned int u32x4;

// Q scale: 1/sqrt(dk) * log2(e)  (softmax computed in exp2 domain)
#define QSCALE 0.1803368801111244f

__device__ __forceinline__ unsigned short f2bf(float f) {
    unsigned u = __builtin_bit_cast(unsigned, f);
    u += 0x7fffu + ((u >> 16) & 1u);
    return (unsigned short)(u >> 16);
}

// ---------------- convert x (fp32 -> bf16) ----------------
__global__ __launch_bounds__(256) void cvt_x_kernel(const float* __restrict__ x,
                                                    unsigned short* __restrict__ xb) {
    size_t i = ((size_t)blockIdx.x * 256 + threadIdx.x) * 8;
    f32x4 a = *(const f32x4*)(x + i);
    f32x4 b = *(const f32x4*)(x + i + 4);
    u16x8 o;
    o[0] = f2bf(a[0]); o[1] = f2bf(a[1]); o[2] = f2bf(a[2]); o[3] = f2bf(a[3]);
    o[4] = f2bf(b[0]); o[5] = f2bf(b[1]); o[6] = f2bf(b[2]); o[7] = f2bf(b[3]);
    *(u16x8*)(xb + i) = o;
}

// ------------- transpose+convert W[k][n] -> W^T[n][k] bf16 -------------
__global__ __launch_bounds__(256) void cvt_wt_kernel(const float* __restrict__ Wq,
                                                     const float* __restrict__ Wk,
                                                     const float* __restrict__ Wv,
                                                     unsigned short* __restrict__ wt) {
    __shared__ float tile[32][33];
    int mat = blockIdx.z;
    const float* W = (mat == 0) ? Wq : (mat == 1) ? Wk : Wv;
    int n0 = blockIdx.x * 32;
    int k0 = blockIdx.y * 32;
    int tx = threadIdx.x;       // 0..31
    int ty = threadIdx.y;       // 0..7
    #pragma unroll
    for (int i = 0; i < 4; ++i)
        tile[ty + i*8][tx] = W[(size_t)(k0 + ty + i*8) * D_MODEL + n0 + tx];
    __syncthreads();
    unsigned short* dst = wt + (size_t)mat * D_MODEL * D_MODEL;
    #pragma unroll
    for (int i = 0; i < 4; ++i)
        dst[(size_t)(n0 + ty + i*8) * D_MODEL + k0 + tx] = f2bf(tile[tx][ty + i*8]);
}

// ---------------- QKV projection GEMM ----------------
// Q,K stored as [b][h][s][dk]; V stored TRANSPOSED as [b][h][dk][s].
#define BM 128
#define BN 128
#define BKK 64
__global__ __launch_bounds__(256) void qkv_gemm_kernel(const unsigned short* __restrict__ xb,
                                                       const unsigned short* __restrict__ wt,
                                                       const float* __restrict__ bq,
                                                       const float* __restrict__ bk,
                                                       const float* __restrict__ bv,
                                                       unsigned short* __restrict__ qkv) {
    __shared__ __align__(16) unsigned char sA[BM * BKK * 2];
    __shared__ __align__(16) unsigned char sB[BN * BKK * 2];

    int nb   = blockIdx.x;            // 0..23
    int mb   = blockIdx.y;            // 0..63
    int mat  = nb >> 3;
    int col0 = (nb & 7) * BN;
    int m0   = mb * BM;
    int t    = threadIdx.x;
    int lane = t & 63;
    int w    = t >> 6;

    const unsigned short* wmat = wt + (size_t)mat * D_MODEL * D_MODEL;
    const float* bias = (mat == 0) ? bq : (mat == 1) ? bk : bv;

    f32x4 acc[4][4];
    #pragma unroll
    for (int i = 0; i < 4; ++i)
        #pragma unroll
        for (int j = 0; j < 4; ++j)
            acc[i][j] = (f32x4)0.0f;

    int rA = (w >> 1) * 64;
    int rB = (w & 1) * 64;

    for (int ks = 0; ks < D_MODEL / BKK; ++ks) {
        int K0 = ks * BKK;
        #pragma unroll
        for (int i = 0; i < 4; ++i) {
            int c   = t + 256 * i;
            int row = c >> 3;
            int kc  = c & 7;
            int swz = kc ^ (row & 7);
            const unsigned short* ga = xb + (size_t)(m0 + row) * D_MODEL + K0 + swz * 8;
            __builtin_amdgcn_global_load_lds(
                (const __attribute__((address_space(1))) void*)ga,
                (__attribute__((address_space(3))) void*)(sA + c * 16), 16, 0, 0);
            const unsigned short* gb = wmat + (size_t)(col0 + row) * D_MODEL + K0 + swz * 8;
            __builtin_amdgcn_global_load_lds(
                (const __attribute__((address_space(1))) void*)gb,
                (__attribute__((address_space(3))) void*)(sB + c * 16), 16, 0, 0);
        }
        __syncthreads();

        #pragma unroll
        for (int kk = 0; kk < 2; ++kk) {
            bf16x8 af[4], bf[4];
            int kc = kk * 4 + (lane >> 4);
            #pragma unroll
            for (int mt = 0; mt < 4; ++mt) {
                int row = rA + mt * 16 + (lane & 15);
                int swz = kc ^ (row & 7);
                af[mt] = *(const bf16x8*)(sA + row * 128 + swz * 16);
            }
            #pragma unroll
            for (int nt = 0; nt < 4; ++nt) {
                int row = rB + nt * 16 + (lane & 15);
                int swz = kc ^ (row & 7);
                bf[nt] = *(const bf16x8*)(sB + row * 128 + swz * 16);
            }
            #pragma unroll
            for (int mt = 0; mt < 4; ++mt)
                #pragma unroll
                for (int nt = 0; nt < 4; ++nt)
                    acc[mt][nt] = __builtin_amdgcn_mfma_f32_16x16x32_bf16(
                        af[mt], bf[nt], acc[mt][nt], 0, 0, 0);
        }
        __syncthreads();
    }

    #pragma unroll
    for (int mt = 0; mt < 4; ++mt) {
        #pragma unroll
        for (int nt = 0; nt < 4; ++nt) {
            int gn = col0 + rB + nt * 16 + (lane & 15);
            float bval = bias[gn];
            #pragma unroll
            for (int r = 0; r < 4; ++r) {
                int gm = m0 + rA + mt * 16 + (lane >> 4) * 4 + r;
                float v = acc[mt][nt][r] + bval;
                if (mat == 0) v *= QSCALE;   // fold 1/sqrt(dk)*log2e into Q
                int b = gm >> 11, s = gm & 2047;
                int h = gn >> 6,  d = gn & 63;
                size_t idx;
                if (mat == 2)   // V transposed: [b][h][d][s]
                    idx = ((size_t)(b * NHEAD + h) * DK + d) * SEQ + s;
                else            // Q,K: [b][h][s][d]
                    idx = ((size_t)(b * NHEAD + h) * SEQ + s) * DK + d;
                qkv[(size_t)mat * MTOT * D_MODEL + idx] = f2bf(v);
            }
        }
    }
}

// ---------------- fused flash attention (swapped-QK^T, 32x32 MFMA, LDS-staged) ----------------
// grid: (64 bh, 8 q-blocks of 256), 512 threads = 8 waves, each wave 32 q-rows.
// EXACT round-6 math (max-tracked defer-max softmax, per-tile cross-half l shfl,
// scatter V store) — ONLY structural change vs round 6 is 8 waves per block.
// LDS map: [0,8192) K buf0 | [8192,16384) K buf1 | [16384,24576) V^T buf0 | [24576,32768) V^T buf1
#define CVTPK(dst, lo_, hi_) \
    asm("v_cvt_pk_bf16_f32 %0, %1, %2" : "=v"(dst) : "v"(lo_), "v"(hi_))
#define PLSWAP(x_, y_) \
    asm("v_permlane32_swap_b32 %0, %1" : "+v"(x_), "+v"(y_))
#define EXP2(dst, x_) \
    asm("v_exp_f32 %0, %1" : "=v"(dst) : "v"(x_))

// P^T B-frag from 8 per-lane P values (C-layout kv rows) via cvt_pk+permlane32_swap.
__device__ __forceinline__ bf16x8 make_pf(float p0, float p1, float p2, float p3,
                                          float p4, float p5, float p6, float p7) {
    unsigned a1, a2, b1, b2;
    CVTPK(a1, p0, p1); CVTPK(a2, p2, p3);
    CVTPK(b1, p4, p5); CVTPK(b2, p6, p7);
    PLSWAP(a1, b1); PLSWAP(a2, b2);
    u32x4 u = { a1, a2, b1, b2 };
    return __builtin_bit_cast(bf16x8, u);
}

__device__ __forceinline__ float vmax16(const f32x16& v) {
    float a = fmaxf(fmaxf(v[0], v[1]),   fmaxf(v[2], v[3]));
    float b = fmaxf(fmaxf(v[4], v[5]),   fmaxf(v[6], v[7]));
    float c = fmaxf(fmaxf(v[8], v[9]),   fmaxf(v[10], v[11]));
    float d = fmaxf(fmaxf(v[12], v[13]), fmaxf(v[14], v[15]));
    return fmaxf(fmaxf(a, b), fmaxf(c, d));
}

__global__ __launch_bounds__(512, 2) void attn_kernel(const unsigned short* __restrict__ qkv,
                                                      float* __restrict__ out) {
    __shared__ __align__(16) unsigned char lds[32768];

    int bh = blockIdx.x;      // b*16 + h
    int qb = blockIdx.y;      // 0..7
    int t = threadIdx.x;      // 0..511
    int lane = t & 63;
    int w = t >> 6;           // 0..7
    int hi = lane >> 5;       // 0/1
    int l31 = lane & 31;

    const unsigned short* Qb = qkv + (size_t)bh * SEQ * DK;
    const unsigned short* Kb = qkv + (size_t)MTOT * D_MODEL + (size_t)bh * SEQ * DK;
    const unsigned short* Vt = qkv + (size_t)2 * MTOT * D_MODEL + (size_t)bh * DK * SEQ; // [d][s]

    int qbase = qb * 256 + w * 32;

    // Q B-frags: col=q=lane&31, k=d=kd*16+hi*8+j   (Q pre-scaled by 1/8*log2e)
    bf16x8 aq[4];
    #pragma unroll
    for (int kd = 0; kd < 4; ++kd)
        aq[kd] = *(const bf16x8*)(Qb + (size_t)(qbase + l31) * DK + kd * 16 + hi * 8);

    f32x16 o0 = (f32x16)0.0f, o1 = (f32x16)0.0f;   // O^T[d][q], d-halves 0/1
    float mrun = -3e38f, lrun = 0.0f;

    // Stage one KV tile: 512 threads x (1 K-chunk + 1 V-chunk of 16B).
#define STAGE(tile_, bo_) do {                                                         \
    int kv0_ = (tile_) * KVB;                                                          \
    int row_ = t >> 3, kc_ = t & 7;                                                    \
    int sw_ = (kc_ ^ (row_ & 7)) * 8;                                                  \
    __builtin_amdgcn_global_load_lds(                                                  \
        (const __attribute__((address_space(1))) void*)(Kb + (size_t)(kv0_ + row_) * DK + sw_), \
        (__attribute__((address_space(3))) void*)(lds + (bo_) + t * 16), 16, 0, 0);             \
    __builtin_amdgcn_global_load_lds(                                                  \
        (const __attribute__((address_space(1))) void*)(Vt + (size_t)row_ * SEQ + kv0_ + sw_),  \
        (__attribute__((address_space(3))) void*)(lds + 16384 + (bo_) + t * 16), 16, 0, 0);     \
} while (0)

    int swz7 = l31 & 7;
    int cofs0 = ((0 + hi) ^ swz7) << 4;
    int cofs1 = ((2 + hi) ^ swz7) << 4;
    int cofs2 = ((4 + hi) ^ swz7) << 4;
    int cofs3 = ((6 + hi) ^ swz7) << 4;

    STAGE(0, 0);
    __syncthreads();
    int buf = 0;

    for (int kt = 0; kt < NT; ++kt) {
        if (kt + 1 < NT)
            STAGE(kt + 1, (buf ^ 1) * 8192);

        const unsigned char* kb = lds + buf * 8192;
        const unsigned char* vb = lds + 16384 + buf * 8192;
        const unsigned char* kr0 = kb + l31 * 128;
        const unsigned char* kr1 = kb + (32 + l31) * 128;
        const unsigned char* vr0 = vb + l31 * 128;
        const unsigned char* vr1 = vb + (32 + l31) * 128;

        // ---- S^T = K Q^T ----
        bf16x8 ak00 = *(const bf16x8*)(kr0 + cofs0);
        bf16x8 ak01 = *(const bf16x8*)(kr0 + cofs1);
        bf16x8 ak02 = *(const bf16x8*)(kr0 + cofs2);
        bf16x8 ak03 = *(const bf16x8*)(kr0 + cofs3);
        bf16x8 ak10 = *(const bf16x8*)(kr1 + cofs0);
        bf16x8 ak11 = *(const bf16x8*)(kr1 + cofs1);
        bf16x8 ak12 = *(const bf16x8*)(kr1 + cofs2);
        bf16x8 ak13 = *(const bf16x8*)(kr1 + cofs3);
        f32x16 sc0 = (f32x16)0.0f, sc1 = (f32x16)0.0f;
        __builtin_amdgcn_s_setprio(1);
        sc0 = __builtin_amdgcn_mfma_f32_32x32x16_bf16(ak00, aq[0], sc0, 0, 0, 0);
        sc1 = __builtin_amdgcn_mfma_f32_32x32x16_bf16(ak10, aq[0], sc1, 0, 0, 0);
        sc0 = __builtin_amdgcn_mfma_f32_32x32x16_bf16(ak01, aq[1], sc0, 0, 0, 0);
        sc1 = __builtin_amdgcn_mfma_f32_32x32x16_bf16(ak11, aq[1], sc1, 0, 0, 0);
        sc0 = __builtin_amdgcn_mfma_f32_32x32x16_bf16(ak02, aq[2], sc0, 0, 0, 0);
        sc1 = __builtin_amdgcn_mfma_f32_32x32x16_bf16(ak12, aq[2], sc1, 0, 0, 0);
        sc0 = __builtin_amdgcn_mfma_f32_32x32x16_bf16(ak03, aq[3], sc0, 0, 0, 0);
        sc1 = __builtin_amdgcn_mfma_f32_32x32x16_bf16(ak13, aq[3], sc1, 0, 0, 0);
        __builtin_amdgcn_s_setprio(0);

        // ---- V^T frags issued now; latency hides under softmax VALU ----
        bf16x8 av00 = *(const bf16x8*)(vr0 + cofs0);
        bf16x8 av01 = *(const bf16x8*)(vr0 + cofs1);
        bf16x8 av02 = *(const bf16x8*)(vr0 + cofs2);
        bf16x8 av03 = *(const bf16x8*)(vr0 + cofs3);
        bf16x8 av10 = *(const bf16x8*)(vr1 + cofs0);
        bf16x8 av11 = *(const bf16x8*)(vr1 + cofs1);
        bf16x8 av12 = *(const bf16x8*)(vr1 + cofs2);
        bf16x8 av13 = *(const bf16x8*)(vr1 + cofs3);

        // ---- online softmax (exp2 domain), defer-max THR=8 ----
        float mx = fmaxf(vmax16(sc0), vmax16(sc1));
        mx = fmaxf(mx, __shfl_xor(mx, 32));
        if (!__all(mx <= mrun + 8.0f)) {
            float mnew = fmaxf(mrun, mx);
            float al;  EXP2(al, mrun - mnew);
            lrun *= al;
            #pragma unroll
            for (int i = 0; i < 16; ++i) { o0[i] *= al; o1[i] *= al; }
            mrun = mnew;
        }
        #pragma unroll
        for (int i = 0; i < 16; ++i) { float p; EXP2(p, sc0[i] - mrun); sc0[i] = p; }
        #pragma unroll
        for (int i = 0; i < 16; ++i) { float p; EXP2(p, sc1[i] - mrun); sc1[i] = p; }
        float r0 = 0.f, r1 = 0.f, r2 = 0.f, r3 = 0.f;
        #pragma unroll
        for (int i = 0; i < 4; ++i) {
            r0 += sc0[i] + sc1[i];     r1 += sc0[4+i] + sc1[4+i];
            r2 += sc0[8+i] + sc1[8+i]; r3 += sc0[12+i] + sc1[12+i];
        }
        float rs = (r0 + r1) + (r2 + r3);
        rs += __shfl_xor(rs, 32);
        lrun += rs;

        // ---- P^T -> bf16 B-frags ----
        bf16x8 pf0 = make_pf(sc0[0], sc0[1], sc0[2],  sc0[3],  sc0[4],  sc0[5],  sc0[6],  sc0[7]);
        bf16x8 pf1 = make_pf(sc0[8], sc0[9], sc0[10], sc0[11], sc0[12], sc0[13], sc0[14], sc0[15]);
        bf16x8 pf2 = make_pf(sc1[0], sc1[1], sc1[2],  sc1[3],  sc1[4],  sc1[5],  sc1[6],  sc1[7]);
        bf16x8 pf3 = make_pf(sc1[8], sc1[9], sc1[10], sc1[11], sc1[12], sc1[13], sc1[14], sc1[15]);

        // ---- O^T += V^T P^T ----
        __builtin_amdgcn_s_setprio(1);
        o0 = __builtin_amdgcn_mfma_f32_32x32x16_bf16(av00, pf0, o0, 0, 0, 0);
        o1 = __builtin_amdgcn_mfma_f32_32x32x16_bf16(av10, pf0, o1, 0, 0, 0);
        o0 = __builtin_amdgcn_mfma_f32_32x32x16_bf16(av01, pf1, o0, 0, 0, 0);
        o1 = __builtin_amdgcn_mfma_f32_32x32x16_bf16(av11, pf1, o1, 0, 0, 0);
        o0 = __builtin_amdgcn_mfma_f32_32x32x16_bf16(av02, pf2, o0, 0, 0, 0);
        o1 = __builtin_amdgcn_mfma_f32_32x32x16_bf16(av12, pf2, o1, 0, 0, 0);
        o0 = __builtin_amdgcn_mfma_f32_32x32x16_bf16(av03, pf3, o0, 0, 0, 0);
        o1 = __builtin_amdgcn_mfma_f32_32x32x16_bf16(av13, pf3, o1, 0, 0, 0);
        __builtin_amdgcn_s_setprio(0);

        __syncthreads();    // drains staging (vmcnt) + protects buffers
        buf ^= 1;
    }
#undef STAGE

    // ---- epilogue: direct f32x4 stores (C rows are 4-contiguous in d) ----
    int b = bh >> 4, h = bh & 15;
    float rl = 1.0f / lrun;
    float* dst = out + ((size_t)b * SEQ + qbase + l31) * D_MODEL + h * DK;
    #pragma unroll
    for (int g = 0; g < 4; ++g) {
        int d0 = 8 * g + 4 * hi;
        f32x4 v0 = { o0[4*g] * rl, o0[4*g+1] * rl, o0[4*g+2] * rl, o0[4*g+3] * rl };
        *(f32x4*)(dst + d0) = v0;
        f32x4 v1 = { o1[4*g] * rl, o1[4*g+1] * rl, o1[4*g+2] * rl, o1[4*g+3] * rl };
        *(f32x4*)(dst + 32 + d0) = v1;
    }
}

extern "C" void kernel_launch(void* const* d_in, const int* in_sizes, int n_in,
                              void* d_out, int out_size, void* d_ws, size_t ws_size,
                              hipStream_t stream) {
    const float* x  = (const float*)d_in[0];
    const float* Wq = (const float*)d_in[1];
    const float* bq = (const float*)d_in[2];
    const float* Wk = (const float*)d_in[3];
    const float* bk = (const float*)d_in[4];
    const float* Wv = (const float*)d_in[5];
    const float* bv = (const float*)d_in[6];
    float* out = (float*)d_out;

    unsigned short* xb  = (unsigned short*)d_ws;                       // 16 MB
    unsigned short* wt  = xb + (size_t)MTOT * D_MODEL;                 // 6 MB
    unsigned short* qkv = wt + (size_t)3 * D_MODEL * D_MODEL;          // 48 MB

    cvt_x_kernel<<<dim3(MTOT * D_MODEL / (256 * 8)), dim3(256), 0, stream>>>(x, xb);
    cvt_wt_kernel<<<dim3(32, 32, 3), dim3(32, 8), 0, stream>>>(Wq, Wk, Wv, wt);
    qkv_gemm_kernel<<<dim3(24, 64), dim3(256), 0, stream>>>(xb, wt, bq, bk, bv, qkv);
    attn_kernel<<<dim3(64, 8), dim3(512), 0, stream>>>(qkv, out);
}

// Round 11
// 198.815 us; speedup vs baseline: 2.5984x; 1.0109x over previous
//
#include <hip/hip_runtime.h>
#include <stdint.h>

#define D_MODEL 1024
#define NHEAD   16
#define DK      64
#define BATCH   4
#define SEQ     2048
#define MTOT    (BATCH*SEQ)   // 8192
#define KVB     64
#define NT      (SEQ/KVB)     // 32

typedef __attribute__((ext_vector_type(4)))  float  f32x4;
typedef __attribute__((ext_vector_type(16))) float  f32x16;
typedef __attribute__((ext_vector_type(8)))  __bf16 bf16x8;
typedef __attribute__((ext_vector_type(8)))  unsigned short u16x8;
typedef __attribute__((ext_vector_type(4)))  unsigned int u32x4;

// Q scale: 1/sqrt(dk) * log2(e)  (softmax computed in exp2 domain)
#define QSCALE 0.1803368801111244f

__device__ __forceinline__ unsigned short f2bf(float f) {
    unsigned u = __builtin_bit_cast(unsigned, f);
    u += 0x7fffu + ((u >> 16) & 1u);
    return (unsigned short)(u >> 16);
}

// ---------------- convert x (fp32 -> bf16) ----------------
__global__ __launch_bounds__(256) void cvt_x_kernel(const float* __restrict__ x,
                                                    unsigned short* __restrict__ xb) {
    size_t i = ((size_t)blockIdx.x * 256 + threadIdx.x) * 8;
    f32x4 a = *(const f32x4*)(x + i);
    f32x4 b = *(const f32x4*)(x + i + 4);
    u16x8 o;
    o[0] = f2bf(a[0]); o[1] = f2bf(a[1]); o[2] = f2bf(a[2]); o[3] = f2bf(a[3]);
    o[4] = f2bf(b[0]); o[5] = f2bf(b[1]); o[6] = f2bf(b[2]); o[7] = f2bf(b[3]);
    *(u16x8*)(xb + i) = o;
}

// ------------- transpose+convert W[k][n] -> W^T[n][k] bf16 -------------
__global__ __launch_bounds__(256) void cvt_wt_kernel(const float* __restrict__ Wq,
                                                     const float* __restrict__ Wk,
                                                     const float* __restrict__ Wv,
                                                     unsigned short* __restrict__ wt) {
    __shared__ float tile[32][33];
    int mat = blockIdx.z;
    const float* W = (mat == 0) ? Wq : (mat == 1) ? Wk : Wv;
    int n0 = blockIdx.x * 32;
    int k0 = blockIdx.y * 32;
    int tx = threadIdx.x;       // 0..31
    int ty = threadIdx.y;       // 0..7
    #pragma unroll
    for (int i = 0; i < 4; ++i)
        tile[ty + i*8][tx] = W[(size_t)(k0 + ty + i*8) * D_MODEL + n0 + tx];
    __syncthreads();
    unsigned short* dst = wt + (size_t)mat * D_MODEL * D_MODEL;
    #pragma unroll
    for (int i = 0; i < 4; ++i)
        dst[(size_t)(n0 + ty + i*8) * D_MODEL + k0 + tx] = f2bf(tile[tx][ty + i*8]);
}

// ---------------- QKV projection GEMM ----------------
// Q,K stored as [b][h][s][dk]; V stored TRANSPOSED as [b][h][dk][s].
// Bijective XCD swizzle (1536 blocks = 8 * 192): blocks sharing an A-panel
// land on the same XCD -> A-panel L2 reuse.
#define BM 128
#define BN 128
#define BKK 64
__global__ __launch_bounds__(256) void qkv_gemm_kernel(const unsigned short* __restrict__ xb,
                                                       const unsigned short* __restrict__ wt,
                                                       const float* __restrict__ bq,
                                                       const float* __restrict__ bk,
                                                       const float* __restrict__ bv,
                                                       unsigned short* __restrict__ qkv) {
    __shared__ __align__(16) unsigned char sA[BM * BKK * 2];
    __shared__ __align__(16) unsigned char sB[BN * BKK * 2];

    int lin = blockIdx.y * 24 + blockIdx.x;          // 0..1535
    lin = (lin & 7) * 192 + (lin >> 3);              // bijective XCD-chunk swizzle
    int nb   = lin % 24;
    int mb   = lin / 24;
    int mat  = nb >> 3;
    int col0 = (nb & 7) * BN;
    int m0   = mb * BM;
    int t    = threadIdx.x;
    int lane = t & 63;
    int w    = t >> 6;

    const unsigned short* wmat = wt + (size_t)mat * D_MODEL * D_MODEL;
    const float* bias = (mat == 0) ? bq : (mat == 1) ? bk : bv;

    f32x4 acc[4][4];
    #pragma unroll
    for (int i = 0; i < 4; ++i)
        #pragma unroll
        for (int j = 0; j < 4; ++j)
            acc[i][j] = (f32x4)0.0f;

    int rA = (w >> 1) * 64;
    int rB = (w & 1) * 64;

    for (int ks = 0; ks < D_MODEL / BKK; ++ks) {
        int K0 = ks * BKK;
        #pragma unroll
        for (int i = 0; i < 4; ++i) {
            int c   = t + 256 * i;
            int row = c >> 3;
            int kc  = c & 7;
            int swz = kc ^ (row & 7);
            const unsigned short* ga = xb + (size_t)(m0 + row) * D_MODEL + K0 + swz * 8;
            __builtin_amdgcn_global_load_lds(
                (const __attribute__((address_space(1))) void*)ga,
                (__attribute__((address_space(3))) void*)(sA + c * 16), 16, 0, 0);
            const unsigned short* gb = wmat + (size_t)(col0 + row) * D_MODEL + K0 + swz * 8;
            __builtin_amdgcn_global_load_lds(
                (const __attribute__((address_space(1))) void*)gb,
                (__attribute__((address_space(3))) void*)(sB + c * 16), 16, 0, 0);
        }
        __syncthreads();

        #pragma unroll
        for (int kk = 0; kk < 2; ++kk) {
            bf16x8 af[4], bf[4];
            int kc = kk * 4 + (lane >> 4);
            #pragma unroll
            for (int mt = 0; mt < 4; ++mt) {
                int row = rA + mt * 16 + (lane & 15);
                int swz = kc ^ (row & 7);
                af[mt] = *(const bf16x8*)(sA + row * 128 + swz * 16);
            }
            #pragma unroll
            for (int nt = 0; nt < 4; ++nt) {
                int row = rB + nt * 16 + (lane & 15);
                int swz = kc ^ (row & 7);
                bf[nt] = *(const bf16x8*)(sB + row * 128 + swz * 16);
            }
            #pragma unroll
            for (int mt = 0; mt < 4; ++mt)
                #pragma unroll
                for (int nt = 0; nt < 4; ++nt)
                    acc[mt][nt] = __builtin_amdgcn_mfma_f32_16x16x32_bf16(
                        af[mt], bf[nt], acc[mt][nt], 0, 0, 0);
        }
        __syncthreads();
    }

    #pragma unroll
    for (int mt = 0; mt < 4; ++mt) {
        #pragma unroll
        for (int nt = 0; nt < 4; ++nt) {
            int gn = col0 + rB + nt * 16 + (lane & 15);
            float bval = bias[gn];
            #pragma unroll
            for (int r = 0; r < 4; ++r) {
                int gm = m0 + rA + mt * 16 + (lane >> 4) * 4 + r;
                float v = acc[mt][nt][r] + bval;
                if (mat == 0) v *= QSCALE;   // fold 1/sqrt(dk)*log2e into Q
                int b = gm >> 11, s = gm & 2047;
                int h = gn >> 6,  d = gn & 63;
                size_t idx;
                if (mat == 2)   // V transposed: [b][h][d][s]
                    idx = ((size_t)(b * NHEAD + h) * DK + d) * SEQ + s;
                else            // Q,K: [b][h][s][d]
                    idx = ((size_t)(b * NHEAD + h) * SEQ + s) * DK + d;
                qkv[(size_t)mat * MTOT * D_MODEL + idx] = f2bf(v);
            }
        }
    }
}

// ---------------- fused flash attention (swapped-QK^T, 32x32 MFMA, LDS-staged) ----------------
// grid: (64 bh, 8 q-blocks of 256), 512 threads = 8 waves, each wave 32 q-rows.
// r9 math exactly. NEW: triple-buffered K/V, staging 2 tiles ahead, counted
// s_waitcnt vmcnt(2) + raw s_barrier (T4: prefetch stays in flight across the
// barrier; never drain to 0 in the main loop).
// LDS: K bufs [0,24576) = 3 x 8K | V^T bufs [24576,49152) = 3 x 8K
#define CVTPK(dst, lo_, hi_) \
    asm("v_cvt_pk_bf16_f32 %0, %1, %2" : "=v"(dst) : "v"(lo_), "v"(hi_))
#define PLSWAP(x_, y_) \
    asm("v_permlane32_swap_b32 %0, %1" : "+v"(x_), "+v"(y_))
#define EXP2(dst, x_) \
    asm("v_exp_f32 %0, %1" : "=v"(dst) : "v"(x_))

// P^T B-frag from 8 per-lane P values (C-layout kv rows) via cvt_pk+permlane32_swap.
__device__ __forceinline__ bf16x8 make_pf(float p0, float p1, float p2, float p3,
                                          float p4, float p5, float p6, float p7) {
    unsigned a1, a2, b1, b2;
    CVTPK(a1, p0, p1); CVTPK(a2, p2, p3);
    CVTPK(b1, p4, p5); CVTPK(b2, p6, p7);
    PLSWAP(a1, b1); PLSWAP(a2, b2);
    u32x4 u = { a1, a2, b1, b2 };
    return __builtin_bit_cast(bf16x8, u);
}

// max of 16 via v_max3-fusable nests (T17)
__device__ __forceinline__ float vmax16(const f32x16& v) {
    float a = fmaxf(fmaxf(v[0],  v[1]),  v[2]);
    float b = fmaxf(fmaxf(v[3],  v[4]),  v[5]);
    float c = fmaxf(fmaxf(v[6],  v[7]),  v[8]);
    float d = fmaxf(fmaxf(v[9],  v[10]), v[11]);
    a = fmaxf(fmaxf(a, v[12]), v[13]);
    b = fmaxf(fmaxf(b, v[14]), v[15]);
    return fmaxf(fmaxf(a, b), fmaxf(c, d));
}

__global__ __launch_bounds__(512, 2) void attn_kernel(const unsigned short* __restrict__ qkv,
                                                      float* __restrict__ out) {
    __shared__ __align__(16) unsigned char lds[49152];

    int bh = blockIdx.x;      // b*16 + h
    int qb = blockIdx.y;      // 0..7
    int t = threadIdx.x;      // 0..511
    int lane = t & 63;
    int w = t >> 6;           // 0..7
    int hi = lane >> 5;       // 0/1
    int l31 = lane & 31;

    const unsigned short* Qb = qkv + (size_t)bh * SEQ * DK;
    const unsigned short* Kb = qkv + (size_t)MTOT * D_MODEL + (size_t)bh * SEQ * DK;
    const unsigned short* Vt = qkv + (size_t)2 * MTOT * D_MODEL + (size_t)bh * DK * SEQ; // [d][s]

    int qbase = qb * 256 + w * 32;

    // Q B-frags: col=q=lane&31, k=d=kd*16+hi*8+j   (Q pre-scaled by 1/8*log2e)
    bf16x8 aq[4];
    #pragma unroll
    for (int kd = 0; kd < 4; ++kd)
        aq[kd] = *(const bf16x8*)(Qb + (size_t)(qbase + l31) * DK + kd * 16 + hi * 8);

    f32x16 o0 = (f32x16)0.0f, o1 = (f32x16)0.0f;   // O^T[d][q], d-halves 0/1
    float mrun = -3e38f, lrun = 0.0f;

    // Stage tile into buffer slot b_: per thread 1 K-chunk + 1 V-chunk (16B each).
#define STAGE(tile_, b_) do {                                                          \
    int kv0_ = (tile_) * KVB;                                                          \
    int row_ = t >> 3, kc_ = t & 7;                                                    \
    int sw_ = (kc_ ^ (row_ & 7)) * 8;                                                  \
    __builtin_amdgcn_global_load_lds(                                                  \
        (const __attribute__((address_space(1))) void*)(Kb + (size_t)(kv0_ + row_) * DK + sw_), \
        (__attribute__((address_space(3))) void*)(lds + (b_) * 8192 + t * 16), 16, 0, 0);       \
    __builtin_amdgcn_global_load_lds(                                                  \
        (const __attribute__((address_space(1))) void*)(Vt + (size_t)row_ * SEQ + kv0_ + sw_),  \
        (__attribute__((address_space(3))) void*)(lds + 24576 + (b_) * 8192 + t * 16), 16, 0, 0); \
} while (0)

    int swz7 = l31 & 7;
    int cofs0 = ((0 + hi) ^ swz7) << 4;
    int cofs1 = ((2 + hi) ^ swz7) << 4;
    int cofs2 = ((4 + hi) ^ swz7) << 4;
    int cofs3 = ((6 + hi) ^ swz7) << 4;

    // Prologue: stage tiles 0 and 1; wait only tile 0 (keep tile 1 in flight).
    STAGE(0, 0);
    STAGE(1, 1);
    asm volatile("s_waitcnt vmcnt(2)" ::: "memory");
    __builtin_amdgcn_s_barrier();

    int b0 = 0, b1 = 1, b2 = 2;   // current / next / stage-target buffer slots

    for (int kt = 0; kt < NT; ++kt) {
        if (kt + 2 < NT)
            STAGE(kt + 2, b2);

        const unsigned char* kb = lds + b0 * 8192;
        const unsigned char* vb = lds + 24576 + b0 * 8192;
        const unsigned char* kr0 = kb + l31 * 128;
        const unsigned char* kr1 = kb + (32 + l31) * 128;
        const unsigned char* vr0 = vb + l31 * 128;
        const unsigned char* vr1 = vb + (32 + l31) * 128;

        // ---- S^T = K Q^T ----
        bf16x8 ak00 = *(const bf16x8*)(kr0 + cofs0);
        bf16x8 ak01 = *(const bf16x8*)(kr0 + cofs1);
        bf16x8 ak02 = *(const bf16x8*)(kr0 + cofs2);
        bf16x8 ak03 = *(const bf16x8*)(kr0 + cofs3);
        bf16x8 ak10 = *(const bf16x8*)(kr1 + cofs0);
        bf16x8 ak11 = *(const bf16x8*)(kr1 + cofs1);
        bf16x8 ak12 = *(const bf16x8*)(kr1 + cofs2);
        bf16x8 ak13 = *(const bf16x8*)(kr1 + cofs3);
        f32x16 sc0 = (f32x16)0.0f, sc1 = (f32x16)0.0f;
        __builtin_amdgcn_s_setprio(1);
        sc0 = __builtin_amdgcn_mfma_f32_32x32x16_bf16(ak00, aq[0], sc0, 0, 0, 0);
        sc1 = __builtin_amdgcn_mfma_f32_32x32x16_bf16(ak10, aq[0], sc1, 0, 0, 0);
        sc0 = __builtin_amdgcn_mfma_f32_32x32x16_bf16(ak01, aq[1], sc0, 0, 0, 0);
        sc1 = __builtin_amdgcn_mfma_f32_32x32x16_bf16(ak11, aq[1], sc1, 0, 0, 0);
        sc0 = __builtin_amdgcn_mfma_f32_32x32x16_bf16(ak02, aq[2], sc0, 0, 0, 0);
        sc1 = __builtin_amdgcn_mfma_f32_32x32x16_bf16(ak12, aq[2], sc1, 0, 0, 0);
        sc0 = __builtin_amdgcn_mfma_f32_32x32x16_bf16(ak03, aq[3], sc0, 0, 0, 0);
        sc1 = __builtin_amdgcn_mfma_f32_32x32x16_bf16(ak13, aq[3], sc1, 0, 0, 0);
        __builtin_amdgcn_s_setprio(0);

        // ---- V^T frags issued now; latency hides under softmax VALU ----
        bf16x8 av00 = *(const bf16x8*)(vr0 + cofs0);
        bf16x8 av01 = *(const bf16x8*)(vr0 + cofs1);
        bf16x8 av02 = *(const bf16x8*)(vr0 + cofs2);
        bf16x8 av03 = *(const bf16x8*)(vr0 + cofs3);
        bf16x8 av10 = *(const bf16x8*)(vr1 + cofs0);
        bf16x8 av11 = *(const bf16x8*)(vr1 + cofs1);
        bf16x8 av12 = *(const bf16x8*)(vr1 + cofs2);
        bf16x8 av13 = *(const bf16x8*)(vr1 + cofs3);

        // ---- online softmax (exp2 domain), defer-max THR=8 ----
        float mx = fmaxf(vmax16(sc0), vmax16(sc1));
        mx = fmaxf(mx, __shfl_xor(mx, 32));
        if (!__all(mx <= mrun + 8.0f)) {
            float mnew = fmaxf(mrun, mx);
            float al;  EXP2(al, mrun - mnew);
            lrun *= al;
            #pragma unroll
            for (int i = 0; i < 16; ++i) { o0[i] *= al; o1[i] *= al; }
            mrun = mnew;
        }
        #pragma unroll
        for (int i = 0; i < 16; ++i) { float p; EXP2(p, sc0[i] - mrun); sc0[i] = p; }
        #pragma unroll
        for (int i = 0; i < 16; ++i) { float p; EXP2(p, sc1[i] - mrun); sc1[i] = p; }
        float r0 = 0.f, r1 = 0.f, r2 = 0.f, r3 = 0.f;
        #pragma unroll
        for (int i = 0; i < 4; ++i) {
            r0 += sc0[i] + sc1[i];     r1 += sc0[4+i] + sc1[4+i];
            r2 += sc0[8+i] + sc1[8+i]; r3 += sc0[12+i] + sc1[12+i];
        }
        float rs = (r0 + r1) + (r2 + r3);
        rs += __shfl_xor(rs, 32);
        lrun += rs;

        // ---- P^T -> bf16 B-frags ----
        bf16x8 pf0 = make_pf(sc0[0], sc0[1], sc0[2],  sc0[3],  sc0[4],  sc0[5],  sc0[6],  sc0[7]);
        bf16x8 pf1 = make_pf(sc0[8], sc0[9], sc0[10], sc0[11], sc0[12], sc0[13], sc0[14], sc0[15]);
        bf16x8 pf2 = make_pf(sc1[0], sc1[1], sc1[2],  sc1[3],  sc1[4],  sc1[5],  sc1[6],  sc1[7]);
        bf16x8 pf3 = make_pf(sc1[8], sc1[9], sc1[10], sc1[11], sc1[12], sc1[13], sc1[14], sc1[15]);

        // ---- O^T += V^T P^T ----
        __builtin_amdgcn_s_setprio(1);
        o0 = __builtin_amdgcn_mfma_f32_32x32x16_bf16(av00, pf0, o0, 0, 0, 0);
        o1 = __builtin_amdgcn_mfma_f32_32x32x16_bf16(av10, pf0, o1, 0, 0, 0);
        o0 = __builtin_amdgcn_mfma_f32_32x32x16_bf16(av01, pf1, o0, 0, 0, 0);
        o1 = __builtin_amdgcn_mfma_f32_32x32x16_bf16(av11, pf1, o1, 0, 0, 0);
        o0 = __builtin_amdgcn_mfma_f32_32x32x16_bf16(av02, pf2, o0, 0, 0, 0);
        o1 = __builtin_amdgcn_mfma_f32_32x32x16_bf16(av12, pf2, o1, 0, 0, 0);
        o0 = __builtin_amdgcn_mfma_f32_32x32x16_bf16(av03, pf3, o0, 0, 0, 0);
        o1 = __builtin_amdgcn_mfma_f32_32x32x16_bf16(av13, pf3, o1, 0, 0, 0);
        __builtin_amdgcn_s_setprio(0);

        // ---- counted-vmcnt barrier: keep this iter's stage in flight ----
        if (kt + 2 < NT) {
            asm volatile("s_waitcnt vmcnt(2)" ::: "memory");   // retire next tile's loads
            __builtin_amdgcn_s_barrier();
        } else if (kt + 1 < NT) {
            asm volatile("s_waitcnt vmcnt(0)" ::: "memory");   // drain for last tile
            __builtin_amdgcn_s_barrier();
        }
        int tb = b0; b0 = b1; b1 = b2; b2 = tb;
    }
#undef STAGE

    // ---- epilogue: direct f32x4 stores (C rows are 4-contiguous in d) ----
    int b = bh >> 4, h = bh & 15;
    float rl = 1.0f / lrun;
    float* dst = out + ((size_t)b * SEQ + qbase + l31) * D_MODEL + h * DK;
    #pragma unroll
    for (int g = 0; g < 4; ++g) {
        int d0 = 8 * g + 4 * hi;
        f32x4 v0 = { o0[4*g] * rl, o0[4*g+1] * rl, o0[4*g+2] * rl, o0[4*g+3] * rl };
        *(f32x4*)(dst + d0) = v0;
        f32x4 v1 = { o1[4*g] * rl, o1[4*g+1] * rl, o1[4*g+2] * rl, o1[4*g+3] * rl };
        *(f32x4*)(dst + 32 + d0) = v1;
    }
}

extern "C" void kernel_launch(void* const* d_in, const int* in_sizes, int n_in,
                              void* d_out, int out_size, void* d_ws, size_t ws_size,
                              hipStream_t stream) {
    const float* x  = (const float*)d_in[0];
    const float* Wq = (const float*)d_in[1];
    const float* bq = (const float*)d_in[2];
    const float* Wk = (const float*)d_in[3];
    const float* bk = (const float*)d_in[4];
    const float* Wv = (const float*)d_in[5];
    const float* bv = (const float*)d_in[6];
    float* out = (float*)d_out;

    unsigned short* xb  = (unsigned short*)d_ws;                       // 16 MB
    unsigned short* wt  = xb + (size_t)MTOT * D_MODEL;                 // 6 MB
    unsigned short* qkv = wt + (size_t)3 * D_MODEL * D_MODEL;          // 48 MB

    cvt_x_kernel<<<dim3(MTOT * D_MODEL / (256 * 8)), dim3(256), 0, stream>>>(x, xb);
    cvt_wt_kernel<<<dim3(32, 32, 3), dim3(32, 8), 0, stream>>>(Wq, Wk, Wv, wt);
    qkv_gemm_kernel<<<dim3(24, 64), dim3(256), 0, stream>>>(xb, wt, bq, bk, bv, qkv);
    attn_kernel<<<dim3(64, 8), dim3(512), 0, stream>>>(qkv, out);
}